// Round 1
// baseline (2110.969 us; speedup 1.0000x reference)
//
#include <hip/hip_runtime.h>

#define N_NODES 50000
#define N_EDGES 600000
#define D 128
#define NC 40

// ---------------- degree / normalization ----------------

__global__ void k_count_deg(const int* __restrict__ dst, int* __restrict__ deg, int nE) {
    int e = blockIdx.x * blockDim.x + threadIdx.x;
    if (e < nE) atomicAdd(&deg[dst[e]], 1);
}

__global__ void k_dinv(const int* __restrict__ deg, float* __restrict__ dinv, int nN) {
    int i = blockIdx.x * blockDim.x + threadIdx.x;
    if (i < nN) dinv[i] = rsqrtf((float)deg[i] + 1.0f);  // +1 = self-loop
}

// ---------------- propagation ----------------

// h_out[i] = dinv[i]^2 * h_in[i]   (self-loop term; also serves as the zero-init)
__global__ void k_selfloop(const float* __restrict__ hin, const float* __restrict__ dinv,
                           float* __restrict__ hout, int nN) {
    int idx = blockIdx.x * blockDim.x + threadIdx.x;  // nN*32 threads, 4 feats each
    int i = idx >> 5;
    int f = (idx & 31) << 2;
    if (i >= nN) return;
    float s = dinv[i];
    s = s * s;
    float4 v = *reinterpret_cast<const float4*>(hin + (size_t)i * D + f);
    v.x *= s; v.y *= s; v.z *= s; v.w *= s;
    *reinterpret_cast<float4*>(hout + (size_t)i * D + f) = v;
}

// h_out[dst] += dinv[src]*dinv[dst] * h_in[src]   (edge-parallel scatter, 32 lanes/edge)
__global__ void k_edge_prop(const int* __restrict__ src, const int* __restrict__ dst,
                            const float* __restrict__ dinv,
                            const float* __restrict__ hin, float* __restrict__ hout, int nE) {
    long long idx = (long long)blockIdx.x * blockDim.x + threadIdx.x;
    long long e = idx >> 5;
    int f = (int)(idx & 31) << 2;
    if (e >= nE) return;
    int s = src[e], d = dst[e];
    float nrm = dinv[s] * dinv[d];
    float4 v = *reinterpret_cast<const float4*>(hin + (size_t)s * D + f);
    float* o = hout + (size_t)d * D + f;
    atomicAdd(o + 0, nrm * v.x);
    atomicAdd(o + 1, nrm * v.y);
    atomicAdd(o + 2, nrm * v.z);
    atomicAdd(o + 3, nrm * v.w);
}

// ---------------- fused epilogue weights: Wf = W_sgc @ W_cls, bf = b_sgc @ W_cls + b_cls ----

__global__ void k_fuse_w(const float* __restrict__ Wsgc, const float* __restrict__ bsgc,
                         const float* __restrict__ Wcls, const float* __restrict__ bcls,
                         float* __restrict__ Wf, float* __restrict__ bf) {
    int idx = blockIdx.x * blockDim.x + threadIdx.x;
    if (idx < D * NC) {
        int k = idx / NC, c = idx % NC;
        float acc = 0.f;
        for (int j = 0; j < D; j++) acc += Wsgc[k * D + j] * Wcls[j * NC + c];
        Wf[idx] = acc;
    } else if (idx < D * NC + NC) {
        int c = idx - D * NC;
        float acc = bcls[c];
        for (int j = 0; j < D; j++) acc += bsgc[j] * Wcls[j * NC + c];
        bf[c] = acc;
    }
}

// ---------------- out = h @ Wf + bf  (50000x128 @ 128x40) ----------------

__global__ void k_out_gemm(const float* __restrict__ h, const float* __restrict__ Wf,
                           const float* __restrict__ bf, float* __restrict__ out, int nN) {
    __shared__ float sW[D * NC];
    for (int t = threadIdx.x; t < D * NC; t += blockDim.x) sW[t] = Wf[t];
    __syncthreads();
    // 320 threads = 8 rows x 40 cols, one output element per thread
    int r = threadIdx.x / NC;
    int c = threadIdx.x % NC;
    if (threadIdx.x >= 8 * NC) return;
    int n = blockIdx.x * 8 + r;
    if (n >= nN) return;
    const float* hr = h + (size_t)n * D;
    float acc = bf[c];
#pragma unroll 8
    for (int k = 0; k < D; k++) acc += hr[k] * sW[k * NC + c];
    out[(size_t)n * NC + c] = acc;
}

// ---------------- launch ----------------

extern "C" void kernel_launch(void* const* d_in, const int* in_sizes, int n_in,
                              void* d_out, int out_size, void* d_ws, size_t ws_size,
                              hipStream_t stream) {
    const float* x    = (const float*)d_in[0];
    const int*   ei   = (const int*)d_in[1];   // [2, E] flat: row0=src, row1=dst
    const float* Wsgc = (const float*)d_in[2];
    const float* bsgc = (const float*)d_in[3];
    const float* Wcls = (const float*)d_in[4];
    const float* bcls = (const float*)d_in[5];
    float* out = (float*)d_out;

    const int* src = ei;
    const int* dst = ei + N_EDGES;

    char* ws = (char*)d_ws;
    size_t off = 0;
    auto alloc = [&](size_t bytes) -> void* {
        void* p = ws + off;
        off += (bytes + 255) & ~255ull;
        return p;
    };
    int*   deg  = (int*)alloc((size_t)N_NODES * 4);
    float* dinv = (float*)alloc((size_t)N_NODES * 4);
    float* h1   = (float*)alloc((size_t)N_NODES * D * 4);
    float* h2   = (float*)alloc((size_t)N_NODES * D * 4);
    float* Wf   = (float*)alloc((size_t)D * NC * 4);
    float* bf   = (float*)alloc((size_t)NC * 4);

    hipMemsetAsync(deg, 0, (size_t)N_NODES * 4, stream);
    k_count_deg<<<(N_EDGES + 255) / 256, 256, 0, stream>>>(dst, deg, N_EDGES);
    k_dinv<<<(N_NODES + 255) / 256, 256, 0, stream>>>(deg, dinv, N_NODES);
    k_fuse_w<<<(D * NC + NC + 255) / 256, 256, 0, stream>>>(Wsgc, bsgc, Wcls, bcls, Wf, bf);

    // hop 1: x -> h1
    k_selfloop<<<((size_t)N_NODES * 32 + 255) / 256, 256, 0, stream>>>(x, dinv, h1, N_NODES);
    k_edge_prop<<<(int)(((long long)N_EDGES * 32 + 255) / 256), 256, 0, stream>>>(
        src, dst, dinv, x, h1, N_EDGES);

    // hop 2: h1 -> h2
    k_selfloop<<<((size_t)N_NODES * 32 + 255) / 256, 256, 0, stream>>>(h1, dinv, h2, N_NODES);
    k_edge_prop<<<(int)(((long long)N_EDGES * 32 + 255) / 256), 256, 0, stream>>>(
        src, dst, dinv, h1, h2, N_EDGES);

    // epilogue: out = h2 @ Wf + bf
    k_out_gemm<<<(N_NODES + 7) / 8, 320, 0, stream>>>(h2, Wf, bf, out, N_NODES);
}

// Round 2
// 232.231 us; speedup vs baseline: 9.0899x; 9.0899x over previous
//
#include <hip/hip_runtime.h>

#define N_NODES 50000
#define N_EDGES 600000
#define D 128
#define NC 40
#define SCAN_BLK 256
#define N_SCAN_BLKS ((N_NODES + SCAN_BLK - 1) / SCAN_BLK)  // 196 <= 256

// ---------------- degree / normalization ----------------

__global__ void k_count_deg(const int* __restrict__ dst, int* __restrict__ deg, int nE) {
    int e = blockIdx.x * blockDim.x + threadIdx.x;
    if (e < nE) atomicAdd(&deg[dst[e]], 1);
}

__global__ void k_dinv(const int* __restrict__ deg, float* __restrict__ dinv, int nN) {
    int i = blockIdx.x * blockDim.x + threadIdx.x;
    if (i < nN) dinv[i] = rsqrtf((float)deg[i] + 1.0f);  // +1 = self-loop
}

// ---------------- 3-kernel exclusive scan of deg -> row_start ----------------

__global__ void k_scan1(const int* __restrict__ deg, int* __restrict__ excl,
                        int* __restrict__ blk_sum, int nN) {
    __shared__ int lds[SCAN_BLK];
    int t = threadIdx.x;
    int i = blockIdx.x * SCAN_BLK + t;
    int v = (i < nN) ? deg[i] : 0;
    lds[t] = v;
    __syncthreads();
    for (int offs = 1; offs < SCAN_BLK; offs <<= 1) {
        int add = (t >= offs) ? lds[t - offs] : 0;
        __syncthreads();
        lds[t] += add;
        __syncthreads();
    }
    if (i < nN) excl[i] = lds[t] - v;
    if (t == SCAN_BLK - 1) blk_sum[blockIdx.x] = lds[t];
}

__global__ void k_scan2(const int* __restrict__ blk_sum, int* __restrict__ blk_off, int nB) {
    __shared__ int lds[SCAN_BLK];
    int t = threadIdx.x;
    int v = (t < nB) ? blk_sum[t] : 0;
    lds[t] = v;
    __syncthreads();
    for (int offs = 1; offs < SCAN_BLK; offs <<= 1) {
        int add = (t >= offs) ? lds[t - offs] : 0;
        __syncthreads();
        lds[t] += add;
        __syncthreads();
    }
    if (t < nB) blk_off[t] = lds[t] - v;
}

__global__ void k_scan3(const int* __restrict__ excl, const int* __restrict__ blk_off,
                        int* __restrict__ row_start, int* __restrict__ cursor, int nN, int nE) {
    int i = blockIdx.x * blockDim.x + threadIdx.x;
    if (i < nN) {
        int r = excl[i] + blk_off[i / SCAN_BLK];
        row_start[i] = r;
        cursor[i] = r;
    }
    if (i == 0) row_start[nN] = nE;
}

// ---------------- CSR fill (by dst): csr_src[pos], csr_w[pos] ----------------

__global__ void k_fill(const int* __restrict__ src, const int* __restrict__ dst,
                       const float* __restrict__ dinv, int* __restrict__ cursor,
                       int* __restrict__ csr_src, float* __restrict__ csr_w, int nE) {
    int e = blockIdx.x * blockDim.x + threadIdx.x;
    if (e >= nE) return;
    int s = src[e], d = dst[e];
    int pos = atomicAdd(&cursor[d], 1);
    csr_src[pos] = s;
    csr_w[pos] = dinv[s] * dinv[d];
}

// ---------------- pull propagation: hout[i] = dinv[i]^2*hin[i] + sum_j w_j*hin[src_j] ----

__global__ void k_pull(const int* __restrict__ row_start, const int* __restrict__ csr_src,
                       const float* __restrict__ csr_w, const float* __restrict__ dinv,
                       const float* __restrict__ hin, float* __restrict__ hout, int nN) {
    // 256 threads = 8 nodes x 32 lanes; each lane owns 4 contiguous feats
    int node = blockIdx.x * 8 + (threadIdx.x >> 5);
    int f = (threadIdx.x & 31) << 2;
    if (node >= nN) return;
    float s = dinv[node];
    s = s * s;
    float4 acc = *reinterpret_cast<const float4*>(hin + (size_t)node * D + f);
    acc.x *= s; acc.y *= s; acc.z *= s; acc.w *= s;
    int beg = row_start[node], end = row_start[node + 1];
    for (int j = beg; j < end; j++) {
        int sn = csr_src[j];
        float w = csr_w[j];
        float4 v = *reinterpret_cast<const float4*>(hin + (size_t)sn * D + f);
        acc.x += w * v.x; acc.y += w * v.y; acc.z += w * v.z; acc.w += w * v.w;
    }
    *reinterpret_cast<float4*>(hout + (size_t)node * D + f) = acc;
}

// ---------------- fused epilogue weights: Wf = W_sgc @ W_cls, bf = b_sgc @ W_cls + b_cls ----

__global__ void k_fuse_w(const float* __restrict__ Wsgc, const float* __restrict__ bsgc,
                         const float* __restrict__ Wcls, const float* __restrict__ bcls,
                         float* __restrict__ Wf, float* __restrict__ bf) {
    int idx = blockIdx.x * blockDim.x + threadIdx.x;
    if (idx < D * NC) {
        int k = idx / NC, c = idx % NC;
        float acc = 0.f;
        for (int j = 0; j < D; j++) acc += Wsgc[k * D + j] * Wcls[j * NC + c];
        Wf[idx] = acc;
    } else if (idx < D * NC + NC) {
        int c = idx - D * NC;
        float acc = bcls[c];
        for (int j = 0; j < D; j++) acc += bsgc[j] * Wcls[j * NC + c];
        bf[c] = acc;
    }
}

// ---------------- out = h @ Wf + bf  (50000x128 @ 128x40) ----------------

__global__ void k_out_gemm(const float* __restrict__ h, const float* __restrict__ Wf,
                           const float* __restrict__ bf, float* __restrict__ out, int nN) {
    __shared__ float sW[D * NC];
    for (int t = threadIdx.x; t < D * NC; t += blockDim.x) sW[t] = Wf[t];
    __syncthreads();
    int r = threadIdx.x / NC;
    int c = threadIdx.x % NC;
    if (threadIdx.x >= 8 * NC) return;
    int n = blockIdx.x * 8 + r;
    if (n >= nN) return;
    const float* hr = h + (size_t)n * D;
    float acc = bf[c];
#pragma unroll 8
    for (int k = 0; k < D; k++) acc += hr[k] * sW[k * NC + c];
    out[(size_t)n * NC + c] = acc;
}

// ---------------- launch ----------------

extern "C" void kernel_launch(void* const* d_in, const int* in_sizes, int n_in,
                              void* d_out, int out_size, void* d_ws, size_t ws_size,
                              hipStream_t stream) {
    const float* x    = (const float*)d_in[0];
    const int*   ei   = (const int*)d_in[1];   // [2, E] flat: row0=src, row1=dst
    const float* Wsgc = (const float*)d_in[2];
    const float* bsgc = (const float*)d_in[3];
    const float* Wcls = (const float*)d_in[4];
    const float* bcls = (const float*)d_in[5];
    float* out = (float*)d_out;

    const int* src = ei;
    const int* dst = ei + N_EDGES;

    char* ws = (char*)d_ws;
    size_t off = 0;
    auto alloc = [&](size_t bytes) -> void* {
        void* p = ws + off;
        off += (bytes + 255) & ~255ull;
        return p;
    };
    int*   deg      = (int*)alloc((size_t)N_NODES * 4);
    float* dinv     = (float*)alloc((size_t)N_NODES * 4);
    int*   excl     = (int*)alloc((size_t)N_NODES * 4);
    int*   blk_sum  = (int*)alloc((size_t)SCAN_BLK * 4);
    int*   blk_off  = (int*)alloc((size_t)SCAN_BLK * 4);
    int*   row_start= (int*)alloc((size_t)(N_NODES + 1) * 4);
    int*   cursor   = (int*)alloc((size_t)N_NODES * 4);
    int*   csr_src  = (int*)alloc((size_t)N_EDGES * 4);
    float* csr_w    = (float*)alloc((size_t)N_EDGES * 4);
    float* h1       = (float*)alloc((size_t)N_NODES * D * 4);
    float* h2       = (float*)alloc((size_t)N_NODES * D * 4);
    float* Wf       = (float*)alloc((size_t)D * NC * 4);
    float* bf       = (float*)alloc((size_t)NC * 4);

    hipMemsetAsync(deg, 0, (size_t)N_NODES * 4, stream);
    k_count_deg<<<(N_EDGES + 255) / 256, 256, 0, stream>>>(dst, deg, N_EDGES);
    k_dinv<<<(N_NODES + 255) / 256, 256, 0, stream>>>(deg, dinv, N_NODES);

    // exclusive scan deg -> row_start (+cursor copy)
    k_scan1<<<N_SCAN_BLKS, SCAN_BLK, 0, stream>>>(deg, excl, blk_sum, N_NODES);
    k_scan2<<<1, SCAN_BLK, 0, stream>>>(blk_sum, blk_off, N_SCAN_BLKS);
    k_scan3<<<(N_NODES + 255) / 256, 256, 0, stream>>>(excl, blk_off, row_start, cursor,
                                                       N_NODES, N_EDGES);

    // CSR fill
    k_fill<<<(N_EDGES + 255) / 256, 256, 0, stream>>>(src, dst, dinv, cursor,
                                                      csr_src, csr_w, N_EDGES);

    // fused epilogue weights (independent, small)
    k_fuse_w<<<(D * NC + NC + 255) / 256, 256, 0, stream>>>(Wsgc, bsgc, Wcls, bcls, Wf, bf);

    // hop 1: x -> h1 ; hop 2: h1 -> h2 (pull, no atomics)
    k_pull<<<(N_NODES + 7) / 8, 256, 0, stream>>>(row_start, csr_src, csr_w, dinv, x, h1, N_NODES);
    k_pull<<<(N_NODES + 7) / 8, 256, 0, stream>>>(row_start, csr_src, csr_w, dinv, h1, h2, N_NODES);

    // epilogue: out = h2 @ Wf + bf
    k_out_gemm<<<(N_NODES + 7) / 8, 320, 0, stream>>>(h2, Wf, bf, out, N_NODES);
}

// Round 3
// 171.049 us; speedup vs baseline: 12.3413x; 1.3577x over previous
//
#include <hip/hip_runtime.h>

#define N_NODES 50000
#define N_EDGES 600000
#define D 128
#define NC 40
#define SCAN_BLK 256
#define N_SCAN_BLKS ((N_NODES + SCAN_BLK - 1) / SCAN_BLK)  // 196 <= 256

// ---------------- degree ----------------

__global__ void k_count_deg(const int* __restrict__ dst, int* __restrict__ deg, int nE) {
    int e = blockIdx.x * blockDim.x + threadIdx.x;
    if (e < nE) atomicAdd(&deg[dst[e]], 1);
}

// ---------------- scan (3-kernel) + dinv folded into pass 1 ----------------

__global__ void k_scan1(const int* __restrict__ deg, int* __restrict__ excl,
                        int* __restrict__ blk_sum, float* __restrict__ dinv, int nN) {
    __shared__ int lds[SCAN_BLK];
    int t = threadIdx.x;
    int i = blockIdx.x * SCAN_BLK + t;
    int v = (i < nN) ? deg[i] : 0;
    if (i < nN) dinv[i] = rsqrtf((float)v + 1.0f);  // +1 = self-loop
    lds[t] = v;
    __syncthreads();
    for (int offs = 1; offs < SCAN_BLK; offs <<= 1) {
        int add = (t >= offs) ? lds[t - offs] : 0;
        __syncthreads();
        lds[t] += add;
        __syncthreads();
    }
    if (i < nN) excl[i] = lds[t] - v;
    if (t == SCAN_BLK - 1) blk_sum[blockIdx.x] = lds[t];
}

__global__ void k_scan2(const int* __restrict__ blk_sum, int* __restrict__ blk_off, int nB) {
    __shared__ int lds[SCAN_BLK];
    int t = threadIdx.x;
    int v = (t < nB) ? blk_sum[t] : 0;
    lds[t] = v;
    __syncthreads();
    for (int offs = 1; offs < SCAN_BLK; offs <<= 1) {
        int add = (t >= offs) ? lds[t - offs] : 0;
        __syncthreads();
        lds[t] += add;
        __syncthreads();
    }
    if (t < nB) blk_off[t] = lds[t] - v;
}

__global__ void k_scan3(const int* __restrict__ excl, const int* __restrict__ blk_off,
                        int* __restrict__ row_start, int* __restrict__ cursor, int nN, int nE) {
    int i = blockIdx.x * blockDim.x + threadIdx.x;
    if (i < nN) {
        int r = excl[i] + blk_off[i / SCAN_BLK];
        row_start[i] = r;
        cursor[i] = r;
    }
    if (i == 0) row_start[nN] = nE;
}

// ---------------- CSR fill (by dst), packed {src, w} ----------------

__global__ void k_fill(const int* __restrict__ src, const int* __restrict__ dst,
                       const float* __restrict__ dinv, int* __restrict__ cursor,
                       int2* __restrict__ csr, int nE) {
    int e = blockIdx.x * blockDim.x + threadIdx.x;
    if (e >= nE) return;
    int s = src[e], d = dst[e];
    float w = dinv[s] * dinv[d];
    int pos = atomicAdd(&cursor[d], 1);
    csr[pos] = make_int2(s, __float_as_int(w));
}

// ---------------- fused weights: Wf = W_sgc @ W_cls, bf = b_sgc @ W_cls + b_cls ----

__global__ void k_fuse_w(const float* __restrict__ Wsgc, const float* __restrict__ bsgc,
                         const float* __restrict__ Wcls, const float* __restrict__ bcls,
                         float* __restrict__ Wf, float* __restrict__ bf) {
    int idx = blockIdx.x * blockDim.x + threadIdx.x;
    if (idx < D * NC) {
        int k = idx / NC, c = idx % NC;
        float acc = 0.f;
        for (int j = 0; j < D; j++) acc += Wsgc[k * D + j] * Wcls[j * NC + c];
        Wf[idx] = acc;
    } else if (idx < D * NC + NC) {
        int c = idx - D * NC;
        float acc = bcls[c];
        for (int j = 0; j < D; j++) acc += bsgc[j] * Wcls[j * NC + c];
        bf[c] = acc;
    }
}

// ---------------- projection: z = x @ Wf  (50000x128 @ 128x40) ----------------

__global__ void k_proj(const float* __restrict__ x, const float* __restrict__ Wf,
                       float* __restrict__ z, int nN) {
    __shared__ float sW[D * NC];   // 20 KB
    __shared__ float sH[8][D];     // 4 KB
    int t = threadIdx.x;  // 320 threads = 8 rows x 40 cols
    for (int q = t; q < D * NC; q += 320) sW[q] = Wf[q];
    // stage 8 rows of x (1024 floats = 256 float4)
    const float4* xr = reinterpret_cast<const float4*>(x + (size_t)blockIdx.x * 8 * D);
    float4* sh4 = reinterpret_cast<float4*>(&sH[0][0]);
    if (t < 256) sh4[t] = xr[t];   // 50000 % 8 == 0, no guard needed
    __syncthreads();
    int r = t / NC, c = t % NC;
    float acc = 0.f;
#pragma unroll
    for (int k = 0; k < D; k++) acc += sH[r][k] * sW[k * NC + c];
    z[((size_t)blockIdx.x * 8 + r) * NC + c] = acc;
}

// ---------------- pull propagation on 40-wide features ----------------
// hout[i] = dinv[i]^2 * hin[i] + sum_j w_j * hin[src_j]   (+ optional bias)
// 10 lanes x float4 per node; 6 groups per wave; 24 nodes per 256-thread block.

__global__ void k_pull40(const int* __restrict__ row_start, const int2* __restrict__ csr,
                         const float* __restrict__ dinv,
                         const float* __restrict__ hin, float* __restrict__ hout,
                         const float* __restrict__ bias, int nN) {
    int wave = threadIdx.x >> 6;
    int lane = threadIdx.x & 63;
    int g = lane / 10;            // 0..5, g==6 idle (lanes 60..63)
    int l = lane - g * 10;
    int node = blockIdx.x * 24 + wave * 6 + g;
    if (g >= 6 || node >= nN) return;
    int f = l << 2;               // feat 0..36
    float s = dinv[node];
    s = s * s;
    float4 acc = *reinterpret_cast<const float4*>(hin + (size_t)node * NC + f);
    acc.x *= s; acc.y *= s; acc.z *= s; acc.w *= s;
    int j = row_start[node], end = row_start[node + 1];
    for (; j + 2 <= end; j += 2) {
        int2 e0 = csr[j], e1 = csr[j + 1];
        float w0 = __int_as_float(e0.y), w1 = __int_as_float(e1.y);
        float4 v0 = *reinterpret_cast<const float4*>(hin + (size_t)e0.x * NC + f);
        float4 v1 = *reinterpret_cast<const float4*>(hin + (size_t)e1.x * NC + f);
        acc.x += w0 * v0.x; acc.y += w0 * v0.y; acc.z += w0 * v0.z; acc.w += w0 * v0.w;
        acc.x += w1 * v1.x; acc.y += w1 * v1.y; acc.z += w1 * v1.z; acc.w += w1 * v1.w;
    }
    if (j < end) {
        int2 e0 = csr[j];
        float w0 = __int_as_float(e0.y);
        float4 v0 = *reinterpret_cast<const float4*>(hin + (size_t)e0.x * NC + f);
        acc.x += w0 * v0.x; acc.y += w0 * v0.y; acc.z += w0 * v0.z; acc.w += w0 * v0.w;
    }
    if (bias) {
        float4 b = *reinterpret_cast<const float4*>(bias + f);
        acc.x += b.x; acc.y += b.y; acc.z += b.z; acc.w += b.w;
    }
    *reinterpret_cast<float4*>(hout + (size_t)node * NC + f) = acc;
}

// ---------------- launch ----------------

extern "C" void kernel_launch(void* const* d_in, const int* in_sizes, int n_in,
                              void* d_out, int out_size, void* d_ws, size_t ws_size,
                              hipStream_t stream) {
    const float* x    = (const float*)d_in[0];
    const int*   ei   = (const int*)d_in[1];   // [2, E] flat: row0=src, row1=dst
    const float* Wsgc = (const float*)d_in[2];
    const float* bsgc = (const float*)d_in[3];
    const float* Wcls = (const float*)d_in[4];
    const float* bcls = (const float*)d_in[5];
    float* out = (float*)d_out;

    const int* src = ei;
    const int* dst = ei + N_EDGES;

    char* ws = (char*)d_ws;
    size_t off = 0;
    auto alloc = [&](size_t bytes) -> void* {
        void* p = ws + off;
        off += (bytes + 255) & ~255ull;
        return p;
    };
    int*   deg      = (int*)alloc((size_t)N_NODES * 4);
    float* dinv     = (float*)alloc((size_t)N_NODES * 4);
    int*   excl     = (int*)alloc((size_t)N_NODES * 4);
    int*   blk_sum  = (int*)alloc((size_t)SCAN_BLK * 4);
    int*   blk_off  = (int*)alloc((size_t)SCAN_BLK * 4);
    int*   row_start= (int*)alloc((size_t)(N_NODES + 1) * 4);
    int*   cursor   = (int*)alloc((size_t)N_NODES * 4);
    int2*  csr      = (int2*)alloc((size_t)N_EDGES * 8);
    float* z0       = (float*)alloc((size_t)N_NODES * NC * 4);
    float* z1       = (float*)alloc((size_t)N_NODES * NC * 4);
    float* Wf       = (float*)alloc((size_t)D * NC * 4);
    float* bf       = (float*)alloc((size_t)NC * 4);

    hipMemsetAsync(deg, 0, (size_t)N_NODES * 4, stream);
    k_count_deg<<<(N_EDGES + 255) / 256, 256, 0, stream>>>(dst, deg, N_EDGES);

    // scan deg -> row_start (+cursor), dinv folded into pass 1
    k_scan1<<<N_SCAN_BLKS, SCAN_BLK, 0, stream>>>(deg, excl, blk_sum, dinv, N_NODES);
    k_scan2<<<1, SCAN_BLK, 0, stream>>>(blk_sum, blk_off, N_SCAN_BLKS);
    k_scan3<<<(N_NODES + 255) / 256, 256, 0, stream>>>(excl, blk_off, row_start, cursor,
                                                       N_NODES, N_EDGES);

    // CSR fill (packed)
    k_fill<<<(N_EDGES + 255) / 256, 256, 0, stream>>>(src, dst, dinv, cursor, csr, N_EDGES);

    // fused weights, then project x down to 40 feats BEFORE propagation
    k_fuse_w<<<(D * NC + NC + 255) / 256, 256, 0, stream>>>(Wsgc, bsgc, Wcls, bcls, Wf, bf);
    k_proj<<<N_NODES / 8, 320, 0, stream>>>(x, Wf, z0, N_NODES);

    // 2 hops on 40-wide features; hop 2 fuses bias and writes d_out directly
    k_pull40<<<(N_NODES + 23) / 24, 256, 0, stream>>>(row_start, csr, dinv, z0, z1,
                                                      nullptr, N_NODES);
    k_pull40<<<(N_NODES + 23) / 24, 256, 0, stream>>>(row_start, csr, dinv, z1, out,
                                                      bf, N_NODES);
}